// Round 1
// baseline (358.884 us; speedup 1.0000x reference)
//
#include <hip/hip_runtime.h>
#include <hip/hip_bf16.h>
#include <stdint.h>

// VQ: inputs [32,512,256] f32, codebook [8192,256] f32.
// out = concat(quantized_st [4194304] f32, loss [1] f32)

#define NE   8192
#define DIM  256
#define NROW 16384
#define NELEM 4194304

typedef __attribute__((ext_vector_type(8))) short short8;
typedef __attribute__((ext_vector_type(4))) float f32x4;
typedef __attribute__((ext_vector_type(4))) unsigned short u16x4;

// workspace layout (bytes)
#define WS_X    0u           // bf16 inputs   8 MB
#define WS_CB   8388608u     // bf16 codebook 4 MB
#define WS_NORM 12582912u    // f32 norms     32 KB
#define WS_AMIN 12615680u    // u64 argmin    128 KB
#define WS_LOSS 12746752u    // f32 loss accumulator

__device__ __forceinline__ unsigned short f2b(float f) {
  // bf16 round-to-nearest-even (inputs are finite; no NaN path needed)
  unsigned u = __float_as_uint(f);
  return (unsigned short)((u + 0x7fffu + ((u >> 16) & 1u)) >> 16);
}

__device__ __forceinline__ void async16(const void* g, void* l) {
  __builtin_amdgcn_global_load_lds(
      (const __attribute__((address_space(1))) void*)g,
      (__attribute__((address_space(3))) void*)l, 16, 0, 0);
}

// ---------------- prep: bf16 casts + code norms + init ----------------
__global__ void vq_prep(const float* __restrict__ x, const float* __restrict__ cb,
                        unsigned short* __restrict__ xb, unsigned short* __restrict__ cbb,
                        float* __restrict__ norms, unsigned long long* __restrict__ amin,
                        float* __restrict__ lossAcc) {
  const int bid = blockIdx.x, tid = threadIdx.x;
  if (bid < 2048) {                       // inputs f32 -> bf16, 8 elems/thread
    const int i = (bid * 256 + tid) * 8;
    f32x4 v0 = *(const f32x4*)(x + i);
    f32x4 v1 = *(const f32x4*)(x + i + 4);
    short8 h;
    h[0] = (short)f2b(v0.x); h[1] = (short)f2b(v0.y);
    h[2] = (short)f2b(v0.z); h[3] = (short)f2b(v0.w);
    h[4] = (short)f2b(v1.x); h[5] = (short)f2b(v1.y);
    h[6] = (short)f2b(v1.z); h[7] = (short)f2b(v1.w);
    *(short8*)(xb + i) = h;
  } else if (bid < 4096) {                // codebook -> bf16 + ||e||^2 (wave/row)
    const int w = tid >> 6, lane = tid & 63;
    const int row = (bid - 2048) * 4 + w;
    f32x4 v = *(const f32x4*)(cb + row * DIM + lane * 4);
    u16x4 h;
    h.x = f2b(v.x); h.y = f2b(v.y); h.z = f2b(v.z); h.w = f2b(v.w);
    *(u16x4*)(cbb + row * DIM + lane * 4) = h;
    float s = v.x * v.x + v.y * v.y + v.z * v.z + v.w * v.w;
    #pragma unroll
    for (int m = 1; m <= 32; m <<= 1) s += __shfl_xor(s, m);
    if (lane == 0) norms[row] = s;
  } else {                                // init argmin keys + loss acc
    const int i = (bid - 4096) * 256 + tid;
    amin[i] = ~0ull;
    if (i == 0) *lossAcc = 0.0f;
  }
}

// ---------------- fused GEMM + argmin ----------------
// grid 512: bid&63 = row block (256 rows), bid>>6 = code chunk (1024 codes).
// 4 waves; wave owns 64 rows as 4x 16-row MFMA tiles. A (x rows, bf16) lives
// in 128 VGPRs for the whole K loop. Codebook tiles (16 codes x 256 dims =
// 8 KB) double-buffered in LDS via global_load_lds(16B), counted vmcnt(2).
// LDS XOR-swizzle ((c&7) on 16B columns) kills the 512B-stride bank conflict;
// swizzle applied on BOTH the global source and the ds_read (rule #21).
__global__ __launch_bounds__(256, 2) void vq_argmin(
    const unsigned short* __restrict__ xb, const unsigned short* __restrict__ cbb,
    const float* __restrict__ norms, unsigned long long* __restrict__ amin) {
  __shared__ __align__(16) char ldsbuf[2][8192];
  __shared__ float lds_en[1024];
  const int tid = threadIdx.x;
  const int w = tid >> 6, lane = tid & 63;
  const int c = lane & 15, hi = lane >> 4;
  const int rb = blockIdx.x & 63;
  const int kb = blockIdx.x >> 6;
  const int kbase = kb * 1024;
  const int rowbase = rb * 256 + w * 64;

  // stage this chunk's code norms into LDS (read per tile via ds, keeps the
  // main loop free of compiler-issued VMEM so our vmcnt counting is exact)
  *(f32x4*)(lds_en + tid * 4) = *(const f32x4*)(norms + kbase + tid * 4);

  // A fragments: row = lane&15 within tile, k = 32*d + 8*(lane>>4) + i
  short8 a[4][8];
  #pragma unroll
  for (int rt = 0; rt < 4; ++rt)
    #pragma unroll
    for (int d = 0; d < 8; ++d)
      a[rt][d] = *(const short8*)(xb + (size_t)(rowbase + rt * 16 + c) * DIM + d * 32 + hi * 8);

  float minv[4][4];
  int   mini[4][4];
  #pragma unroll
  for (int rt = 0; rt < 4; ++rt)
    #pragma unroll
    for (int j = 0; j < 4; ++j) { minv[rt][j] = 3.0e38f; mini[rt][j] = 0; }

  __syncthreads();  // lds_en visible; drains all VMEM (A loads included)

  // prologue: stage tile 0 -> buf 0
  {
    const char* gsrc = (const char*)cbb + (size_t)kbase * 512;
    #pragma unroll
    for (int r = 0; r < 2; ++r) {
      const int o = r * 4096 + tid * 16;       // linear LDS offset
      const int crow = o >> 9;                 // code row in tile
      const int col16 = (o >> 4) & 31;         // 16B column
      const int gcol = col16 ^ (crow & 7);     // inverse-swizzled source
      async16(gsrc + crow * 512 + gcol * 16, &ldsbuf[0][r * 4096 + w * 1024]);
    }
  }

  #pragma unroll 2
  for (int t = 0; t < 64; ++t) {
    const int cur = t & 1;
    if (t + 1 < 64) {
      const char* gsrc = (const char*)cbb + (size_t)(kbase + (t + 1) * 16) * 512;
      #pragma unroll
      for (int r = 0; r < 2; ++r) {
        const int o = r * 4096 + tid * 16;
        const int crow = o >> 9;
        const int col16 = (o >> 4) & 31;
        const int gcol = col16 ^ (crow & 7);
        async16(gsrc + crow * 512 + gcol * 16, &ldsbuf[cur ^ 1][r * 4096 + w * 1024]);
      }
      asm volatile("s_waitcnt vmcnt(2)" ::: "memory");  // tile t done; next 2 in flight
    } else {
      asm volatile("s_waitcnt vmcnt(0)" ::: "memory");
    }
    __builtin_amdgcn_s_barrier();

    const float en = lds_en[t * 16 + c];
    f32x4 acc0 = {0.f, 0.f, 0.f, 0.f}, acc1 = acc0, acc2 = acc0, acc3 = acc0;
    #pragma unroll
    for (int d = 0; d < 8; ++d) {
      const int col16 = (d * 4 + hi) ^ (c & 7);  // swizzled read
      short8 b = *(const short8*)(&ldsbuf[cur][c * 512 + col16 * 16]);
      acc0 = __builtin_amdgcn_mfma_f32_16x16x32_bf16(a[0][d], b, acc0, 0, 0, 0);
      acc1 = __builtin_amdgcn_mfma_f32_16x16x32_bf16(a[1][d], b, acc1, 0, 0, 0);
      acc2 = __builtin_amdgcn_mfma_f32_16x16x32_bf16(a[2][d], b, acc2, 0, 0, 0);
      acc3 = __builtin_amdgcn_mfma_f32_16x16x32_bf16(a[3][d], b, acc3, 0, 0, 0);
    }
    // s = ||e||^2 - 2*x.e  (same argmin as full distance)
    const int code = kbase + t * 16 + c;
    #pragma unroll
    for (int j = 0; j < 4; ++j) {
      float s0 = fmaf(-2.f, acc0[j], en);
      if (s0 < minv[0][j]) { minv[0][j] = s0; mini[0][j] = code; }
      float s1 = fmaf(-2.f, acc1[j], en);
      if (s1 < minv[1][j]) { minv[1][j] = s1; mini[1][j] = code; }
      float s2 = fmaf(-2.f, acc2[j], en);
      if (s2 < minv[2][j]) { minv[2][j] = s2; mini[2][j] = code; }
      float s3 = fmaf(-2.f, acc3[j], en);
      if (s3 < minv[3][j]) { minv[3][j] = s3; mini[3][j] = code; }
    }
    __builtin_amdgcn_s_barrier();  // all waves done reading buf before overwrite
  }

  // reduce (min, idx) across the 16 column-lanes sharing each row
  #pragma unroll
  for (int rt = 0; rt < 4; ++rt)
    #pragma unroll
    for (int j = 0; j < 4; ++j) {
      float v = minv[rt][j];
      int idx = mini[rt][j];
      #pragma unroll
      for (int m = 1; m <= 8; m <<= 1) {
        float ov = __shfl_xor(v, m);
        int oi = __shfl_xor(idx, m);
        if (ov < v || (ov == v && oi < idx)) { v = ov; idx = oi; }
      }
      if (c == 0) {
        const int row = rowbase + rt * 16 + hi * 4 + j;
        unsigned ub = __float_as_uint(v);            // monotone f32 -> u32 key
        ub = (ub & 0x80000000u) ? ~ub : (ub | 0x80000000u);
        const unsigned long long key = ((unsigned long long)ub << 32) | (unsigned)idx;
        atomicMin(&amin[row], key);
      }
    }
}

// ---------------- gather + straight-through + loss partials ----------------
__global__ void vq_gather(const float* __restrict__ x, const float* __restrict__ cb,
                          const unsigned long long* __restrict__ amin,
                          float* __restrict__ out, float* __restrict__ lossAcc) {
  const int tid = threadIdx.x;
  const int w = tid >> 6, lane = tid & 63;
  const int r = blockIdx.x * 4 + w;
  const int idx = (int)(unsigned)amin[r];            // low 32 bits = argmin index
  const f32x4 q  = *(const f32x4*)(cb + (size_t)idx * DIM + lane * 4);
  const f32x4 xv = *(const f32x4*)(x + (size_t)r * DIM + lane * 4);
  f32x4 d = q - xv;
  *(f32x4*)(out + (size_t)r * DIM + lane * 4) = xv + d;  // straight-through value
  float s = d.x * d.x + d.y * d.y + d.z * d.z + d.w * d.w;
  #pragma unroll
  for (int m = 1; m <= 32; m <<= 1) s += __shfl_xor(s, m);
  if (lane == 0) atomicAdd(lossAcc, s);
}

__global__ void vq_finalize(const float* __restrict__ lossAcc, float* __restrict__ out) {
  // loss = 0.25*mean((q-x)^2) + mean((q-x)^2) = 1.25 * sum / NELEM
  out[NELEM] = 1.25f * lossAcc[0] * (1.0f / 4194304.0f);
}

extern "C" void kernel_launch(void* const* d_in, const int* in_sizes, int n_in,
                              void* d_out, int out_size, void* d_ws, size_t ws_size,
                              hipStream_t stream) {
  const float* x  = (const float*)d_in[0];
  const float* cb = (const float*)d_in[1];
  float* out = (float*)d_out;
  char* ws = (char*)d_ws;
  unsigned short* xb  = (unsigned short*)(ws + WS_X);
  unsigned short* cbb = (unsigned short*)(ws + WS_CB);
  float* norms = (float*)(ws + WS_NORM);
  unsigned long long* amin = (unsigned long long*)(ws + WS_AMIN);
  float* lossAcc = (float*)(ws + WS_LOSS);

  vq_prep<<<4160, 256, 0, stream>>>(x, cb, xb, cbb, norms, amin, lossAcc);
  vq_argmin<<<512, 256, 0, stream>>>(xb, cbb, norms, amin);
  vq_gather<<<4096, 256, 0, stream>>>(x, cb, amin, out, lossAcc);
  vq_finalize<<<1, 1, 0, stream>>>(lossAcc, out);
}

// Round 2
// 152.468 us; speedup vs baseline: 2.3538x; 2.3538x over previous
//
#include <hip/hip_runtime.h>
#include <hip/hip_bf16.h>
#include <stdint.h>

// VQ: inputs [32,512,256] f32, codebook [8192,256] f32.
// out = concat(quantized_st [4194304] f32, loss [1] f32)

#define NE   8192
#define DIM  256
#define NROW 16384
#define NELEM 4194304

typedef __attribute__((ext_vector_type(8))) short short8;
typedef __attribute__((ext_vector_type(4))) float f32x4;
typedef __attribute__((ext_vector_type(4))) unsigned short u16x4;

// workspace layout (bytes)
#define WS_X    0u           // bf16 inputs   8 MB
#define WS_CB   8388608u     // bf16 codebook 4 MB
#define WS_NORM 12582912u    // f32 norms     32 KB
#define WS_AMIN 12615680u    // u64 argmin    128 KB
#define WS_PART 12746752u    // f32 loss partials [4096]

__device__ __forceinline__ unsigned short f2b(float f) {
  // bf16 round-to-nearest-even (inputs are finite; no NaN path needed)
  unsigned u = __float_as_uint(f);
  return (unsigned short)((u + 0x7fffu + ((u >> 16) & 1u)) >> 16);
}

__device__ __forceinline__ void async16(const void* g, void* l) {
  __builtin_amdgcn_global_load_lds(
      (const __attribute__((address_space(1))) void*)g,
      (__attribute__((address_space(3))) void*)l, 16, 0, 0);
}

// ---------------- prep: bf16 casts + code norms + init ----------------
__global__ void vq_prep(const float* __restrict__ x, const float* __restrict__ cb,
                        unsigned short* __restrict__ xb, unsigned short* __restrict__ cbb,
                        float* __restrict__ norms, unsigned long long* __restrict__ amin) {
  const int bid = blockIdx.x, tid = threadIdx.x;
  if (bid < 2048) {                       // inputs f32 -> bf16, 8 elems/thread
    const int i = (bid * 256 + tid) * 8;
    f32x4 v0 = *(const f32x4*)(x + i);
    f32x4 v1 = *(const f32x4*)(x + i + 4);
    short8 h;
    h[0] = (short)f2b(v0.x); h[1] = (short)f2b(v0.y);
    h[2] = (short)f2b(v0.z); h[3] = (short)f2b(v0.w);
    h[4] = (short)f2b(v1.x); h[5] = (short)f2b(v1.y);
    h[6] = (short)f2b(v1.z); h[7] = (short)f2b(v1.w);
    *(short8*)(xb + i) = h;
  } else if (bid < 4096) {                // codebook -> bf16 + ||e||^2 (wave/row)
    const int w = tid >> 6, lane = tid & 63;
    const int row = (bid - 2048) * 4 + w;
    f32x4 v = *(const f32x4*)(cb + row * DIM + lane * 4);
    u16x4 h;
    h.x = f2b(v.x); h.y = f2b(v.y); h.z = f2b(v.z); h.w = f2b(v.w);
    *(u16x4*)(cbb + row * DIM + lane * 4) = h;
    float s = v.x * v.x + v.y * v.y + v.z * v.z + v.w * v.w;
    #pragma unroll
    for (int m = 1; m <= 32; m <<= 1) s += __shfl_xor(s, m);
    if (lane == 0) norms[row] = s;
  } else {                                // init argmin keys
    const int i = (bid - 4096) * 256 + tid;
    amin[i] = ~0ull;
  }
}

// ---------------- fused GEMM + argmin ----------------
// grid 512: bid&63 = row block (256 rows), bid>>6 = code chunk (1024 codes).
// 4 waves; wave owns 64 rows as 4x 16-row MFMA tiles. A (x rows, bf16) lives
// in 128 VGPRs for the whole K loop. Codebook tiles (16 codes x 256 dims =
// 8 KB) double-buffered in LDS via global_load_lds(16B), counted vmcnt(2).
// LDS XOR-swizzle ((c&7) on 16B columns) kills the 512B-stride bank conflict;
// swizzle applied on BOTH the global source and the ds_read (rule #21).
__global__ __launch_bounds__(256, 2) void vq_argmin(
    const unsigned short* __restrict__ xb, const unsigned short* __restrict__ cbb,
    const float* __restrict__ norms, unsigned long long* __restrict__ amin) {
  __shared__ __align__(16) char ldsbuf[2][8192];
  __shared__ float lds_en[1024];
  const int tid = threadIdx.x;
  const int w = tid >> 6, lane = tid & 63;
  const int c = lane & 15, hi = lane >> 4;
  const int rb = blockIdx.x & 63;
  const int kb = blockIdx.x >> 6;
  const int kbase = kb * 1024;
  const int rowbase = rb * 256 + w * 64;

  // stage this chunk's code norms into LDS (read per tile via ds, keeps the
  // main loop free of compiler-issued VMEM so our vmcnt counting is exact)
  *(f32x4*)(lds_en + tid * 4) = *(const f32x4*)(norms + kbase + tid * 4);

  // A fragments: row = lane&15 within tile, k = 32*d + 8*(lane>>4) + i
  short8 a[4][8];
  #pragma unroll
  for (int rt = 0; rt < 4; ++rt)
    #pragma unroll
    for (int d = 0; d < 8; ++d)
      a[rt][d] = *(const short8*)(xb + (size_t)(rowbase + rt * 16 + c) * DIM + d * 32 + hi * 8);

  float minv[4][4];
  int   mini[4][4];
  #pragma unroll
  for (int rt = 0; rt < 4; ++rt)
    #pragma unroll
    for (int j = 0; j < 4; ++j) { minv[rt][j] = 3.0e38f; mini[rt][j] = 0; }

  __syncthreads();  // lds_en visible; drains all VMEM (A loads included)

  // prologue: stage tile 0 -> buf 0
  {
    const char* gsrc = (const char*)cbb + (size_t)kbase * 512;
    #pragma unroll
    for (int r = 0; r < 2; ++r) {
      const int o = r * 4096 + tid * 16;       // linear LDS offset
      const int crow = o >> 9;                 // code row in tile
      const int col16 = (o >> 4) & 31;         // 16B column
      const int gcol = col16 ^ (crow & 7);     // inverse-swizzled source
      async16(gsrc + crow * 512 + gcol * 16, &ldsbuf[0][r * 4096 + w * 1024]);
    }
  }

  #pragma unroll 2
  for (int t = 0; t < 64; ++t) {
    const int cur = t & 1;
    if (t + 1 < 64) {
      const char* gsrc = (const char*)cbb + (size_t)(kbase + (t + 1) * 16) * 512;
      #pragma unroll
      for (int r = 0; r < 2; ++r) {
        const int o = r * 4096 + tid * 16;
        const int crow = o >> 9;
        const int col16 = (o >> 4) & 31;
        const int gcol = col16 ^ (crow & 7);
        async16(gsrc + crow * 512 + gcol * 16, &ldsbuf[cur ^ 1][r * 4096 + w * 1024]);
      }
      asm volatile("s_waitcnt vmcnt(2)" ::: "memory");  // tile t done; next 2 in flight
    } else {
      asm volatile("s_waitcnt vmcnt(0)" ::: "memory");
    }
    __builtin_amdgcn_s_barrier();

    const float en = lds_en[t * 16 + c];
    f32x4 acc0 = {0.f, 0.f, 0.f, 0.f}, acc1 = acc0, acc2 = acc0, acc3 = acc0;
    #pragma unroll
    for (int d = 0; d < 8; ++d) {
      const int col16 = (d * 4 + hi) ^ (c & 7);  // swizzled read
      short8 b = *(const short8*)(&ldsbuf[cur][c * 512 + col16 * 16]);
      acc0 = __builtin_amdgcn_mfma_f32_16x16x32_bf16(a[0][d], b, acc0, 0, 0, 0);
      acc1 = __builtin_amdgcn_mfma_f32_16x16x32_bf16(a[1][d], b, acc1, 0, 0, 0);
      acc2 = __builtin_amdgcn_mfma_f32_16x16x32_bf16(a[2][d], b, acc2, 0, 0, 0);
      acc3 = __builtin_amdgcn_mfma_f32_16x16x32_bf16(a[3][d], b, acc3, 0, 0, 0);
    }
    // s = ||e||^2 - 2*x.e  (same argmin as full distance)
    const int code = kbase + t * 16 + c;
    #pragma unroll
    for (int j = 0; j < 4; ++j) {
      float s0 = fmaf(-2.f, acc0[j], en);
      if (s0 < minv[0][j]) { minv[0][j] = s0; mini[0][j] = code; }
      float s1 = fmaf(-2.f, acc1[j], en);
      if (s1 < minv[1][j]) { minv[1][j] = s1; mini[1][j] = code; }
      float s2 = fmaf(-2.f, acc2[j], en);
      if (s2 < minv[2][j]) { minv[2][j] = s2; mini[2][j] = code; }
      float s3 = fmaf(-2.f, acc3[j], en);
      if (s3 < minv[3][j]) { minv[3][j] = s3; mini[3][j] = code; }
    }
    __builtin_amdgcn_s_barrier();  // all waves done reading buf before overwrite
  }

  // reduce (min, idx) across the 16 column-lanes sharing each row
  #pragma unroll
  for (int rt = 0; rt < 4; ++rt)
    #pragma unroll
    for (int j = 0; j < 4; ++j) {
      float v = minv[rt][j];
      int idx = mini[rt][j];
      #pragma unroll
      for (int m = 1; m <= 8; m <<= 1) {
        float ov = __shfl_xor(v, m);
        int oi = __shfl_xor(idx, m);
        if (ov < v || (ov == v && oi < idx)) { v = ov; idx = oi; }
      }
      if (c == 0) {
        const int row = rowbase + rt * 16 + hi * 4 + j;
        unsigned ub = __float_as_uint(v);            // monotone f32 -> u32 key
        ub = (ub & 0x80000000u) ? ~ub : (ub | 0x80000000u);
        const unsigned long long key = ((unsigned long long)ub << 32) | (unsigned)idx;
        atomicMin(&amin[row], key);
      }
    }
}

// ---------------- gather + straight-through + loss partials ----------------
// One f32 partial per block (LDS reduce over 4 waves) -> no contended atomics.
__global__ void vq_gather(const float* __restrict__ x, const float* __restrict__ cb,
                          const unsigned long long* __restrict__ amin,
                          float* __restrict__ out, float* __restrict__ partial) {
  __shared__ float wsum[4];
  const int tid = threadIdx.x;
  const int w = tid >> 6, lane = tid & 63;
  const int r = blockIdx.x * 4 + w;
  const int idx = (int)(unsigned)amin[r];            // low 32 bits = argmin index
  const f32x4 q  = *(const f32x4*)(cb + (size_t)idx * DIM + lane * 4);
  const f32x4 xv = *(const f32x4*)(x + (size_t)r * DIM + lane * 4);
  f32x4 d = q - xv;
  *(f32x4*)(out + (size_t)r * DIM + lane * 4) = xv + d;  // straight-through value
  float s = d.x * d.x + d.y * d.y + d.z * d.z + d.w * d.w;
  #pragma unroll
  for (int m = 1; m <= 32; m <<= 1) s += __shfl_xor(s, m);
  if (lane == 0) wsum[w] = s;
  __syncthreads();
  if (tid == 0) partial[blockIdx.x] = wsum[0] + wsum[1] + wsum[2] + wsum[3];
}

__global__ void vq_finalize(const float* __restrict__ partial, float* __restrict__ out) {
  __shared__ float wsum[4];
  const int tid = threadIdx.x;
  float s = 0.0f;
  #pragma unroll
  for (int i = 0; i < 16; ++i) s += partial[i * 256 + tid];
  #pragma unroll
  for (int m = 1; m <= 32; m <<= 1) s += __shfl_xor(s, m);
  if ((tid & 63) == 0) wsum[tid >> 6] = s;
  __syncthreads();
  if (tid == 0)
    out[NELEM] = 1.25f * (wsum[0] + wsum[1] + wsum[2] + wsum[3]) * (1.0f / 4194304.0f);
}

extern "C" void kernel_launch(void* const* d_in, const int* in_sizes, int n_in,
                              void* d_out, int out_size, void* d_ws, size_t ws_size,
                              hipStream_t stream) {
  const float* x  = (const float*)d_in[0];
  const float* cb = (const float*)d_in[1];
  float* out = (float*)d_out;
  char* ws = (char*)d_ws;
  unsigned short* xb  = (unsigned short*)(ws + WS_X);
  unsigned short* cbb = (unsigned short*)(ws + WS_CB);
  float* norms = (float*)(ws + WS_NORM);
  unsigned long long* amin = (unsigned long long*)(ws + WS_AMIN);
  float* partial = (float*)(ws + WS_PART);

  vq_prep<<<4160, 256, 0, stream>>>(x, cb, xb, cbb, norms, amin);
  vq_argmin<<<512, 256, 0, stream>>>(xb, cbb, norms, amin);
  vq_gather<<<4096, 256, 0, stream>>>(x, cb, amin, out, partial);
  vq_finalize<<<1, 256, 0, stream>>>(partial, out);
}